// Round 7
// baseline (33278.900 us; speedup 1.0000x reference)
//
#include <hip/hip_runtime.h>
#include <hip/hip_bf16.h>
#include <math.h>

typedef __hip_bfloat16 bf16;

#define NB 4
#define NS 4096
#define NE 512
#define NH 8
#define NL 4
#define NA 3
#define ND 64
#define NC 64
#define NW 64
#define NF 2048
#define NVOC 17
#define NTOK (NB * NS)   // 16384

__device__ __forceinline__ float b2f(bf16 v) { return __bfloat162float(v); }
__device__ __forceinline__ float u2f(unsigned short u) { return __uint_as_float((unsigned)u << 16); }
// dual-dtype scalar load: f32 ? float : bf16
__device__ __forceinline__ float ldw(const void* p, size_t i, int f32) {
  return f32 ? ((const float*)p)[i] : b2f(((const bf16*)p)[i]);
}

// ---------------- dtype detect + flag init ----------------
// tok_emb row 0 (512 elems) is all zeros (padding_idx=0). As fp32 it spans
// uint words 0..511; as bf16 it spans words 0..255 and words 256..511 hold
// row-1 random data (N(0,1), virtually never all-zero).
__global__ void detect_kernel(const void* __restrict__ tok, int* __restrict__ dflag) {
  if (threadIdx.x == 0 && blockIdx.x == 0) {
    const unsigned* w = (const unsigned*)tok;
    int any = 0;
    for (int i = 256; i < 512; i++) any |= (w[i] != 0u);
    dflag[0] = any ? 0 : 1;   // 1 = fp32 inputs, 0 = bf16 inputs
    dflag[1] = 0;             // NaN stage canary
  }
}

// ---------------- NaN/Inf scan: record first bad stage ----------------
__global__ __launch_bounds__(256) void scan_kernel(const float* __restrict__ buf, int n,
                                                   int stage, int* __restrict__ dflag) {
  int i = blockIdx.x * 256 + threadIdx.x;
  if (i < n) {
    float v = buf[i];
    if (((__float_as_uint(v) >> 23) & 0xFF) == 0xFF) atomicCAS(&dflag[1], 0, stage);
  }
}

// ---------------- diagnostic fill (ws_size too small) ----------------
__global__ __launch_bounds__(256) void fill_out_kernel(bf16* __restrict__ out, int n, float val) {
  int i = blockIdx.x * 256 + threadIdx.x;
  if (i < n) out[i] = __float2bfloat16(val);
}

// ---------------- zero fill ----------------
__global__ __launch_bounds__(256) void zero_kernel(float* __restrict__ p, int n) {
  int i = blockIdx.x * 256 + threadIdx.x;
  if (i < n) p[i] = 0.f;
}

// ---------------- embeddings + shift-right ----------------
__global__ __launch_bounds__(256) void embed_kernel(
    const int* __restrict__ value, const int* __restrict__ depth, const int* __restrict__ pos,
    const void* __restrict__ sos, const void* __restrict__ tok_emb,
    const void* __restrict__ depth_emb, const void* __restrict__ pos_emb,
    float* __restrict__ x, const int* __restrict__ dflag) {
  int f32 = dflag[0];
  int i = blockIdx.x * 256 + threadIdx.x;
  if (i >= NTOK * NE) return;
  int e = i & (NE - 1);
  int bs = i >> 9;
  int s = bs & (NS - 1);
  int b = bs >> 12;
  float v;
  if (s == 0) {
    v = ldw(sos, e, f32);
  } else {
    int src = b * NS + (s - 1);
    float acc = ldw(tok_emb, (size_t)value[src] * NE + e, f32)
              + ldw(depth_emb, (size_t)depth[src] * NE + e, f32);
#pragma unroll
    for (int a = 0; a < NA; a++)
      acc += ldw(pos_emb, ((size_t)a * 65 + pos[src * NA + a]) * NE + e, f32);
    v = acc;
  }
  x[i] = v;
}

// ---------------- layer norm (element-offset gamma/beta) ----------------
__global__ __launch_bounds__(256) void ln_kernel(
    const float* __restrict__ x, const void* __restrict__ gam, const void* __restrict__ bet,
    size_t off, float* __restrict__ out, const int* __restrict__ dflag) {
  __shared__ float buf[256];
  int f32 = dflag[0];
  int row = blockIdx.x;
  int t = threadIdx.x;
  const float* xr = x + (size_t)row * NE;
  float v0 = xr[t], v1 = xr[t + 256];
  buf[t] = v0 + v1;
  __syncthreads();
  for (int s = 128; s; s >>= 1) { if (t < s) buf[t] += buf[t + s]; __syncthreads(); }
  float m = buf[0] * (1.0f / NE);
  __syncthreads();
  float d0 = v0 - m, d1 = v1 - m;
  buf[t] = d0 * d0 + d1 * d1;
  __syncthreads();
  for (int s = 128; s; s >>= 1) { if (t < s) buf[t] += buf[t + s]; __syncthreads(); }
  float rs = 1.0f / sqrtf(buf[0] * (1.0f / NE) + 1e-5f);
  out[(size_t)row * NE + t]       = d0 * rs * ldw(gam, off + t, f32)       + ldw(bet, off + t, f32);
  out[(size_t)row * NE + t + 256] = d1 * rs * ldw(gam, off + t + 256, f32) + ldw(bet, off + t + 256, f32);
}

// ---------------- GEMM: C(MxN) = act(A @ B + bias) [+resid]
// A fp32 MxK; B (bf16|f32) via base+element-offset, row stride ldb
template <int ACT>
__global__ __launch_bounds__(256) void gemm_kernel(
    const float* __restrict__ A, const void* __restrict__ Bw, size_t bwoff, int ldb,
    const void* bias, size_t biasoff, const float* resid, float* C,
    int M, int N, int K, const int* __restrict__ dflag) {
  __shared__ float As[16][68];
  __shared__ float Bs[16][68];
  int f32 = dflag[0];
  int tid = threadIdx.x;
  int bm = blockIdx.y << 6, bn = blockIdx.x << 6;
  int ty = tid >> 4, tx = tid & 15;
  float acc[4][4];
#pragma unroll
  for (int i = 0; i < 4; i++)
#pragma unroll
    for (int j = 0; j < 4; j++) acc[i][j] = 0.f;
  int arow = tid >> 2;
  int akc = (tid & 3) << 2;
  int brow = tid >> 4;
  int bcol = (tid & 15) << 2;
  for (int k0 = 0; k0 < K; k0 += 16) {
    float4 av = *(const float4*)(A + (size_t)(bm + arow) * K + k0 + akc);
    As[akc + 0][arow] = av.x; As[akc + 1][arow] = av.y;
    As[akc + 2][arow] = av.z; As[akc + 3][arow] = av.w;
    size_t boff = bwoff + (size_t)(k0 + brow) * ldb + bn + bcol;
    if (f32) {
      float4 bv = *(const float4*)((const float*)Bw + boff);
      Bs[brow][bcol + 0] = bv.x; Bs[brow][bcol + 1] = bv.y;
      Bs[brow][bcol + 2] = bv.z; Bs[brow][bcol + 3] = bv.w;
    } else {
      union { uint2 u; unsigned short s[4]; } r;
      r.u = *(const uint2*)((const bf16*)Bw + boff);
#pragma unroll
      for (int j = 0; j < 4; j++) Bs[brow][bcol + j] = u2f(r.s[j]);
    }
    __syncthreads();
#pragma unroll
    for (int kk = 0; kk < 16; kk++) {
      float4 a4 = *(const float4*)&As[kk][ty << 2];
      float4 b4 = *(const float4*)&Bs[kk][tx << 2];
      float aa[4] = {a4.x, a4.y, a4.z, a4.w};
      float bb[4] = {b4.x, b4.y, b4.z, b4.w};
#pragma unroll
      for (int i = 0; i < 4; i++)
#pragma unroll
        for (int j = 0; j < 4; j++)
          acc[i][j] += aa[i] * bb[j];
    }
    __syncthreads();
  }
#pragma unroll
  for (int i = 0; i < 4; i++) {
    int row = bm + (ty << 2) + i;
#pragma unroll
    for (int j = 0; j < 4; j++) {
      int col = bn + (tx << 2) + j;
      float v = acc[i][j];
      if (bias) v += ldw(bias, biasoff + col, f32);
      if (ACT == 1) {
        float tgt = 0.7978845608028654f * (v + 0.044715f * v * v * v);
        v = 0.5f * v * (1.0f + tanhf(tgt));
      }
      size_t o = (size_t)row * N + col;
      if (resid) v += resid[o];
      C[o] = v;
    }
  }
}

// ---------------- normalized means in fp64 (shared-tree) ----------------
__global__ __launch_bounds__(64) void mnd_kernel(const void* __restrict__ means,
                                                 double* __restrict__ mnd,
                                                 const int* __restrict__ dflag) {
  __shared__ double s[64];
  int f32 = dflag[0];
  int vblk = blockIdx.x;          // (l*NH + h)*NC + c
  int d = threadIdx.x;
  double m = (double)ldw(means, (size_t)vblk * ND + d, f32);
  s[d] = m * m;
  __syncthreads();
  for (int st = 32; st; st >>= 1) { if (d < st) s[d] += s[d + st]; __syncthreads(); }
  mnd[(size_t)vblk * ND + d] = m / (sqrt(s[0]) + 1e-8);
}

// ---------------- per-token 1/(||q_h||+1e-8), one 64-thread block per token ----------------
__global__ __launch_bounds__(64) void rq_kernel(const float* __restrict__ q, double* __restrict__ rqd) {
  __shared__ double s[64];
  int row = blockIdx.x;
  int d = threadIdx.x;
  double v = (double)q[(size_t)row * ND + d];
  s[d] = v * v;
  __syncthreads();
  for (int st = 32; st; st >>= 1) { if (d < st) s[d] += s[d + st]; __syncthreads(); }
  if (d == 0) rqd[row] = 1.0 / (sqrt(s[0]) + 1e-8);
}

// ---------------- routing for one head: fp64 dists + top-64, lowest-index tiebreak ----------------
__global__ __launch_bounds__(256) void route_kernel(
    const float* __restrict__ q, const double* __restrict__ mnd,
    const double* __restrict__ rqd, int* __restrict__ idxout) {
  __shared__ unsigned long long keys[NS];   // 32 KB
  __shared__ unsigned long long sred[256];  // 2 KB
  __shared__ double mc[ND];
  int blk = blockIdx.x;                     // b*NC + c
  int b = blk >> 6;
  int c = blk & (NC - 1);
  int t = threadIdx.x;
  if (t < ND) mc[t] = mnd[(size_t)c * ND + t];
  __syncthreads();
  for (int n = t; n < NS; n += 256) {
    const float* qp = q + (size_t)(b * NS + n) * ND;
    double acc = 0.0;
#pragma unroll
    for (int d = 0; d < ND; d++) acc += (double)qp[d] * mc[d];
    double dist = acc * rqd[b * NS + n];
    long long sb = __double_as_longlong(dist);
    unsigned long long u = (unsigned long long)sb;
    u = (sb < 0) ? ~u : (u | 0x8000000000000000ULL);
    keys[n] = (u & 0xFFFFFFFFFFFFF000ULL) | (unsigned long long)(NS - 1 - n);
  }
  __syncthreads();
  for (int it = 0; it < NW; it++) {
    unsigned long long best = 0;
    for (int n = t; n < NS; n += 256) { if (keys[n] > best) best = keys[n]; }
    sred[t] = best;
    __syncthreads();
    for (int s = 128; s; s >>= 1) {
      if (t < s && sred[t + s] > sred[t]) sred[t] = sred[t + s];
      __syncthreads();
    }
    if (t == 0) {
      int n = (NS - 1) - (int)(sred[0] & 0xFFFULL);
      idxout[(size_t)blk * NW + it] = n;
      keys[n] = 0;
    }
    __syncthreads();
  }
}

// ---------------- per-token selection count for current head ----------------
__global__ __launch_bounds__(256) void cnt_kernel(const int* __restrict__ idxb, float* __restrict__ cnt) {
  int i = blockIdx.x * 256 + threadIdx.x;   // NB*NC*NW = 16384 exact
  int b = i >> 12;                          // / (NC*NW)
  atomicAdd(&cnt[b * NS + idxb[i]], 1.0f);
}

// ---------------- bucket attention for one head; scatter (attn/cnt) @ Wo_h into xbuf ----------------
__global__ __launch_bounds__(256) void attn_kernel(
    const float* __restrict__ q, const float* __restrict__ k, const float* __restrict__ v,
    const int* __restrict__ idxb, const int* __restrict__ value, const float* __restrict__ cnt,
    const void* __restrict__ wo, size_t wooff, int h, float* __restrict__ xout,
    const int* __restrict__ dflag) {
  __shared__ float qs[NW * (ND + 1)];   // q, later attn@V result
  __shared__ float ks[NW * (ND + 1)];   // k, later v
  __shared__ float sc[NW * (NW + 1)];
  __shared__ int idxs[NW];
  __shared__ float kmv[NW];
  __shared__ float cinv[NW];
  int f32 = dflag[0];
  int blk = blockIdx.x;                 // b*NC + c
  int b = blk >> 6;
  int t = threadIdx.x;
  if (t < NW) {
    int n = idxb[(size_t)blk * NW + t];
    idxs[t] = n;
    kmv[t] = (value[b * NS + n] != 0) ? 1.f : 0.f;
    cinv[t] = 1.0f / fmaxf(cnt[b * NS + n], 1.0f);
  }
  __syncthreads();
  for (int p = t; p < NW * ND; p += 256) {
    int w = p >> 6, d = p & (ND - 1);
    size_t src = (size_t)(b * NS + idxs[w]) * ND + d;
    qs[w * (ND + 1) + d] = q[src];
    ks[w * (ND + 1) + d] = k[src];
  }
  __syncthreads();
  for (int p = t; p < NW * NW; p += 256) {
    int w = p >> 6, x = p & (NW - 1);
    float dot = 0.f;
#pragma unroll 16
    for (int d = 0; d < ND; d++) dot += qs[w * (ND + 1) + d] * ks[x * (ND + 1) + d];
    bool allowed = (idxs[w] >= idxs[x]) && (kmv[x] != 0.f);
    sc[w * (NW + 1) + x] = allowed ? dot * 0.125f : -1e9f;
  }
  __syncthreads();
  // wave 0 does softmax rows (÷cnt folded); other waves stage V into ks (reads of ks are done)
  if (t < NW) {
    float mx = -3.4e38f;
    for (int x = 0; x < NW; x++) mx = fmaxf(mx, sc[t * (NW + 1) + x]);
    float sum = 0.f;
    for (int x = 0; x < NW; x++) {
      float e = expf(sc[t * (NW + 1) + x] - mx);
      sc[t * (NW + 1) + x] = e;
      sum += e;
    }
    float inv = cinv[t] / sum;
    for (int x = 0; x < NW; x++) sc[t * (NW + 1) + x] *= inv;
  }
  for (int p = t; p < NW * ND; p += 256) {
    int w = p >> 6, d = p & (ND - 1);
    ks[w * (ND + 1) + d] = v[(size_t)(b * NS + idxs[w]) * ND + d];
  }
  __syncthreads();
  // P @ V into qs (old qs values dead)
  for (int p = t; p < NW * ND; p += 256) {
    int w = p >> 6, d = p & (ND - 1);
    float o = 0.f;
#pragma unroll 16
    for (int x = 0; x < NW; x++) o += sc[w * (NW + 1) + x] * ks[x * (ND + 1) + d];
    qs[w * (ND + 1) + d] = o;
  }
  __syncthreads();
  // scatter through Wo rows [h*64, h*64+64) into the residual stream
  size_t wbase = wooff + (size_t)h * ND * NE;
  for (int p = t; p < NW * NE; p += 256) {
    int w = p >> 9, j = p & (NE - 1);
    const float* ob = qs + w * (ND + 1);
    float o = 0.f;
#pragma unroll 8
    for (int d = 0; d < ND; d++) o += ob[d] * ldw(wo, wbase + (size_t)d * NE + j, f32);
    atomicAdd(&xout[(size_t)(b * NS + idxs[w]) * NE + j], o);
  }
}

// ---------------- head: out[b,s,v] = x . head_w[v]; canary-aware, dtype-aware ----------------
__global__ __launch_bounds__(256) void head_kernel(
    const float* __restrict__ x, const void* __restrict__ hw, void* __restrict__ out,
    const int* __restrict__ dflag) {
  int f32 = dflag[0];
  int bad = dflag[1];
  int gw = (blockIdx.x * 256 + threadIdx.x) >> 6;
  int lane = threadIdx.x & 63;
  if (gw >= NTOK * NVOC) return;
  int row = gw / NVOC, vv = gw % NVOC;
  float acc;
  if (bad) {
    acc = (float)bad * 10000.0f;   // encode first NaN stage into absmax
  } else {
    const float* xr = x + (size_t)row * NE;
    acc = 0.f;
    for (int e = lane; e < NE; e += 64) acc += xr[e] * ldw(hw, (size_t)vv * NE + e, f32);
#pragma unroll
    for (int o = 32; o; o >>= 1) acc += __shfl_down(acc, o);
  }
  if (lane == 0) {
    if (f32) ((float*)out)[(size_t)row * NVOC + vv] = acc;
    else ((bf16*)out)[(size_t)row * NVOC + vv] = __float2bfloat16(acc);
  }
}

extern "C" void kernel_launch(void* const* d_in, const int* in_sizes, int n_in,
                              void* d_out, int out_size, void* d_ws, size_t ws_size,
                              hipStream_t stream) {
  const int* value = (const int*)d_in[0];
  const int* depth = (const int*)d_in[1];
  const int* pos = (const int*)d_in[2];
  const void* sos = d_in[3];
  const void* tok_emb = d_in[4];
  const void* depth_emb = d_in[5];
  const void* pos_emb = d_in[6];
  const void* ln1_s = d_in[7];
  const void* ln1_b = d_in[8];
  const void* Wq = d_in[9];
  const void* Wk = d_in[10];
  const void* Wv = d_in[11];
  const void* Wo = d_in[12];
  const void* means = d_in[13];
  const void* ln2_s = d_in[14];
  const void* ln2_b = d_in[15];
  const void* W1 = d_in[16];
  const void* b1 = d_in[17];
  const void* W2 = d_in[18];
  const void* b2 = d_in[19];
  const void* head_w = d_in[20];
  (void)in_sizes; (void)n_in;

  const size_t NX = (size_t)NTOK * NE;                 // 8,388,608 floats (32 MiB)
  const size_t SLAB = (size_t)NTOK * ND;               // 1,048,576 floats (4 MiB)

  const size_t NEED = (78ULL << 20);
  if (ws_size < NEED) {
    float val = (float)(unsigned)(ws_size >> 20) * 1000.0f;
    fill_out_kernel<<<(out_size + 255) / 256, 256, 0, stream>>>((bf16*)d_out, out_size, val);
    return;
  }

  float* xbuf = (float*)d_ws;                          // 32 MiB residual stream
  float* hbuf = xbuf + NX;                             // 32 MiB LN output
  float* scr  = hbuf + NX;                             // 12 MiB scratch
  float* sq = scr;                                     // per-head q (4 MiB)
  float* sk = scr + SLAB;                              // per-head k (4 MiB)
  float* sv = scr + 2 * SLAB;                          // per-head v (4 MiB)
  float* mid = scr;                                    // FFN mid chunk 1024x2048 (8 MiB; q/k/v dead)
  double* mndbuf = (double*)(scr + 3 * SLAB);                      // 1 MiB
  double* rqdbuf = mndbuf + (size_t)NL * NH * NC * ND;             // 128 KiB
  float* cntbuf = (float*)(rqdbuf + NTOK);                         // 64 KiB
  int* idxbuf = (int*)(cntbuf + NTOK);                             // 64 KiB
  int* dflag = idxbuf + (size_t)NB * NC * NW;                      // 2 ints

  detect_kernel<<<1, 64, 0, stream>>>(tok_emb, dflag);
  mnd_kernel<<<NL * NH * NC, 64, 0, stream>>>(means, mndbuf, dflag);
  embed_kernel<<<(int)((NX + 255) / 256), 256, 0, stream>>>(
      value, depth, pos, sos, tok_emb, depth_emb, pos_emb, xbuf, dflag);
  scan_kernel<<<(int)((NX + 255) / 256), 256, 0, stream>>>(xbuf, (int)NX, 1, dflag);

  const int CH = 1024;                        // FFN row chunk (mid = CH x NF = 8 MiB)

  for (int l = 0; l < NL; l++) {
    size_t o_w = (size_t)l * NE * NE;
    size_t o_w1 = (size_t)l * NE * NF;
    size_t o_w2 = (size_t)l * NF * NE;
    size_t o_e = (size_t)l * NE;
    size_t o_f = (size_t)l * NF;

    ln_kernel<<<NTOK, 256, 0, stream>>>(xbuf, ln1_s, ln1_b, o_e, hbuf, dflag);
    if (l == 0) scan_kernel<<<(int)((NX + 255) / 256), 256, 0, stream>>>(hbuf, (int)NX, 2, dflag);

    for (int h = 0; h < NH; h++) {
      dim3 gqkv(1, NTOK / 64);
      gemm_kernel<0><<<gqkv, 256, 0, stream>>>(hbuf, Wq, o_w + h * ND, NE, nullptr, 0, nullptr,
                                               sq, NTOK, ND, NE, dflag);
      gemm_kernel<0><<<gqkv, 256, 0, stream>>>(hbuf, Wk, o_w + h * ND, NE, nullptr, 0, nullptr,
                                               sk, NTOK, ND, NE, dflag);
      gemm_kernel<0><<<gqkv, 256, 0, stream>>>(hbuf, Wv, o_w + h * ND, NE, nullptr, 0, nullptr,
                                               sv, NTOK, ND, NE, dflag);
      if (l == 0 && h == 0)
        scan_kernel<<<(int)((SLAB + 255) / 256), 256, 0, stream>>>(sq, (int)SLAB, 3, dflag);

      rq_kernel<<<NTOK, 64, 0, stream>>>(sq, rqdbuf);
      route_kernel<<<NB * NC, 256, 0, stream>>>(
          sq, mndbuf + ((size_t)l * NH + h) * NC * ND, rqdbuf, idxbuf);

      zero_kernel<<<NTOK / 256, 256, 0, stream>>>(cntbuf, NTOK);
      cnt_kernel<<<(NB * NC * NW) / 256, 256, 0, stream>>>(idxbuf, cntbuf);

      attn_kernel<<<NB * NC, 256, 0, stream>>>(sq, sk, sv, idxbuf, value, cntbuf,
                                               Wo, o_w, h, xbuf, dflag);
    }
    if (l == 0) scan_kernel<<<(int)((NX + 255) / 256), 256, 0, stream>>>(xbuf, (int)NX, 4, dflag);

    ln_kernel<<<NTOK, 256, 0, stream>>>(xbuf, ln2_s, ln2_b, o_e, hbuf, dflag);

    for (int ch = 0; ch < NTOK / CH; ch++) {
      const float* hch = hbuf + (size_t)ch * CH * NE;
      float* xch = xbuf + (size_t)ch * CH * NE;
      gemm_kernel<1><<<dim3(NF / 64, CH / 64), 256, 0, stream>>>(
          hch, W1, o_w1, NF, b1, o_f, nullptr, mid, CH, NF, NE, dflag);
      gemm_kernel<0><<<dim3(NE / 64, CH / 64), 256, 0, stream>>>(
          mid, W2, o_w2, NE, b2, o_e, xch, xch, CH, NE, NF, dflag);
    }
    if (l == 0) scan_kernel<<<(int)((NX + 255) / 256), 256, 0, stream>>>(xbuf, (int)NX, 5, dflag);
  }

  scan_kernel<<<(int)((NX + 255) / 256), 256, 0, stream>>>(xbuf, (int)NX, 6, dflag);
  head_kernel<<<(NTOK * NVOC * 64 + 255) / 256, 256, 0, stream>>>(xbuf, head_w, d_out, dflag);
}

// Round 8
// 9368.049 us; speedup vs baseline: 3.5524x; 3.5524x over previous
//
#include <hip/hip_runtime.h>
#include <hip/hip_bf16.h>
#include <math.h>

typedef __hip_bfloat16 bf16;

#define NB 4
#define NS 4096
#define NE 512
#define NH 8
#define NL 4
#define NA 3
#define ND 64
#define NC 64
#define NW 64
#define NF 2048
#define NVOC 17
#define NTOK (NB * NS)   // 16384

__device__ __forceinline__ float b2f(bf16 v) { return __bfloat162float(v); }
__device__ __forceinline__ float u2f(unsigned short u) { return __uint_as_float((unsigned)u << 16); }
// dual-dtype scalar load: f32 ? float : bf16
__device__ __forceinline__ float ldw(const void* p, size_t i, int f32) {
  return f32 ? ((const float*)p)[i] : b2f(((const bf16*)p)[i]);
}

// ---------------- dtype detect (tok_emb row 0 all-zero <=> fp32 spans words 0..511) ----------------
__global__ void detect_kernel(const void* __restrict__ tok, int* __restrict__ dflag) {
  if (threadIdx.x == 0 && blockIdx.x == 0) {
    const unsigned* w = (const unsigned*)tok;
    int any = 0;
    for (int i = 256; i < 512; i++) any |= (w[i] != 0u);
    dflag[0] = any ? 0 : 1;   // 1 = fp32 inputs, 0 = bf16 inputs
  }
}

// ---------------- diagnostic fill (ws_size too small) ----------------
__global__ __launch_bounds__(256) void fill_out_kernel(float* __restrict__ out, int n, float val) {
  int i = blockIdx.x * 256 + threadIdx.x;
  if (i < n) out[i] = val;
}

// ---------------- zero fill ----------------
__global__ __launch_bounds__(256) void zero_kernel(float* __restrict__ p, int n) {
  int i = blockIdx.x * 256 + threadIdx.x;
  if (i < n) p[i] = 0.f;
}

// ---------------- embeddings + shift-right ----------------
__global__ __launch_bounds__(256) void embed_kernel(
    const int* __restrict__ value, const int* __restrict__ depth, const int* __restrict__ pos,
    const void* __restrict__ sos, const void* __restrict__ tok_emb,
    const void* __restrict__ depth_emb, const void* __restrict__ pos_emb,
    float* __restrict__ x, const int* __restrict__ dflag) {
  int f32 = dflag[0];
  int i = blockIdx.x * 256 + threadIdx.x;
  if (i >= NTOK * NE) return;
  int e = i & (NE - 1);
  int bs = i >> 9;
  int s = bs & (NS - 1);
  int b = bs >> 12;
  float v;
  if (s == 0) {
    v = ldw(sos, e, f32);
  } else {
    int src = b * NS + (s - 1);
    float acc = ldw(tok_emb, (size_t)value[src] * NE + e, f32)
              + ldw(depth_emb, (size_t)depth[src] * NE + e, f32);
#pragma unroll
    for (int a = 0; a < NA; a++)
      acc += ldw(pos_emb, ((size_t)a * 65 + pos[src * NA + a]) * NE + e, f32);
    v = acc;
  }
  x[i] = v;
}

// ---------------- layer norm (element-offset gamma/beta) ----------------
__global__ __launch_bounds__(256) void ln_kernel(
    const float* __restrict__ x, const void* __restrict__ gam, const void* __restrict__ bet,
    size_t off, float* __restrict__ out, const int* __restrict__ dflag) {
  __shared__ float buf[256];
  int f32 = dflag[0];
  int row = blockIdx.x;
  int t = threadIdx.x;
  const float* xr = x + (size_t)row * NE;
  float v0 = xr[t], v1 = xr[t + 256];
  buf[t] = v0 + v1;
  __syncthreads();
  for (int s = 128; s; s >>= 1) { if (t < s) buf[t] += buf[t + s]; __syncthreads(); }
  float m = buf[0] * (1.0f / NE);
  __syncthreads();
  float d0 = v0 - m, d1 = v1 - m;
  buf[t] = d0 * d0 + d1 * d1;
  __syncthreads();
  for (int s = 128; s; s >>= 1) { if (t < s) buf[t] += buf[t + s]; __syncthreads(); }
  float rs = 1.0f / sqrtf(buf[0] * (1.0f / NE) + 1e-5f);
  out[(size_t)row * NE + t]       = d0 * rs * ldw(gam, off + t, f32)       + ldw(bet, off + t, f32);
  out[(size_t)row * NE + t + 256] = d1 * rs * ldw(gam, off + t + 256, f32) + ldw(bet, off + t + 256, f32);
}

// ---------------- GEMM 128x128 tile, 8x8 microtile ----------------
// C(MxN) = act(A @ B + bias) [+resid]; A fp32 MxK; B (bf16|f32) base+elem offset, row stride ldb.
// M % 128 == 0, N % 128 == 0, K % 16 == 0 (true for all uses here).
template <int ACT>
__global__ __launch_bounds__(256) void gemm_kernel(
    const float* __restrict__ A, const void* __restrict__ Bw, size_t bwoff, int ldb,
    const void* bias, size_t biasoff, const float* resid, float* C,
    int M, int N, int K, const int* __restrict__ dflag) {
  __shared__ float As[16][132];   // [k][m], row len 132 (mult of 4 -> aligned float4)
  __shared__ float Bs[16][132];   // [k][n]
  int f32 = dflag[0];
  int tid = threadIdx.x;
  int bm = blockIdx.y << 7, bn = blockIdx.x << 7;
  int ty = tid >> 4, tx = tid & 15;
  float acc[8][8];
#pragma unroll
  for (int i = 0; i < 8; i++)
#pragma unroll
    for (int j = 0; j < 8; j++) acc[i][j] = 0.f;
  int arow = tid >> 1;
  int acol = (tid & 1) << 3;
  int brow = tid >> 4;
  int bcol = (tid & 15) << 3;
  for (int k0 = 0; k0 < K; k0 += 16) {
    const float* Ap = A + (size_t)(bm + arow) * K + k0 + acol;
    float4 a0 = *(const float4*)Ap;
    float4 a1 = *(const float4*)(Ap + 4);
    As[acol + 0][arow] = a0.x; As[acol + 1][arow] = a0.y;
    As[acol + 2][arow] = a0.z; As[acol + 3][arow] = a0.w;
    As[acol + 4][arow] = a1.x; As[acol + 5][arow] = a1.y;
    As[acol + 6][arow] = a1.z; As[acol + 7][arow] = a1.w;
    size_t boff = bwoff + (size_t)(k0 + brow) * ldb + bn + bcol;
    if (f32) {
      const float* Bp = (const float*)Bw + boff;
      float4 b0 = *(const float4*)Bp;
      float4 b1 = *(const float4*)(Bp + 4);
      Bs[brow][bcol + 0] = b0.x; Bs[brow][bcol + 1] = b0.y;
      Bs[brow][bcol + 2] = b0.z; Bs[brow][bcol + 3] = b0.w;
      Bs[brow][bcol + 4] = b1.x; Bs[brow][bcol + 5] = b1.y;
      Bs[brow][bcol + 6] = b1.z; Bs[brow][bcol + 7] = b1.w;
    } else {
      union { uint4 u; unsigned short s[8]; } r;
      r.u = *(const uint4*)((const bf16*)Bw + boff);
#pragma unroll
      for (int j = 0; j < 8; j++) Bs[brow][bcol + j] = u2f(r.s[j]);
    }
    __syncthreads();
#pragma unroll
    for (int kk = 0; kk < 16; kk++) {
      float4 aA = *(const float4*)&As[kk][ty << 3];
      float4 aB = *(const float4*)&As[kk][(ty << 3) + 4];
      float4 bA = *(const float4*)&Bs[kk][tx << 3];
      float4 bB = *(const float4*)&Bs[kk][(tx << 3) + 4];
      float av[8] = {aA.x, aA.y, aA.z, aA.w, aB.x, aB.y, aB.z, aB.w};
      float bv[8] = {bA.x, bA.y, bA.z, bA.w, bB.x, bB.y, bB.z, bB.w};
#pragma unroll
      for (int i = 0; i < 8; i++)
#pragma unroll
        for (int j = 0; j < 8; j++)
          acc[i][j] += av[i] * bv[j];
    }
    __syncthreads();
  }
#pragma unroll
  for (int i = 0; i < 8; i++) {
    int row = bm + (ty << 3) + i;
    size_t base = (size_t)row * N + bn + (tx << 3);
#pragma unroll
    for (int j = 0; j < 8; j++) {
      float vv = acc[i][j];
      if (bias) vv += ldw(bias, biasoff + bn + (tx << 3) + j, f32);
      if (ACT == 1) {
        float tgt = 0.7978845608028654f * (vv + 0.044715f * vv * vv * vv);
        vv = 0.5f * vv * (1.0f + tanhf(tgt));
      }
      if (resid) vv += resid[base + j];
      C[base + j] = vv;
    }
  }
}

// ---------------- normalized means in fp64 ----------------
__global__ __launch_bounds__(64) void mnd_kernel(const void* __restrict__ means,
                                                 double* __restrict__ mnd,
                                                 const int* __restrict__ dflag) {
  __shared__ double s[64];
  int f32 = dflag[0];
  int vblk = blockIdx.x;          // (l*NH + h)*NC + c
  int d = threadIdx.x;
  double m = (double)ldw(means, (size_t)vblk * ND + d, f32);
  s[d] = m * m;
  __syncthreads();
  for (int st = 32; st; st >>= 1) { if (d < st) s[d] += s[d + st]; __syncthreads(); }
  mnd[(size_t)vblk * ND + d] = m / (sqrt(s[0]) + 1e-8);
}

// ---------------- per-(token,head) 1/(||q||+1e-8) over full q ----------------
__global__ __launch_bounds__(64) void rq_kernel(const float* __restrict__ q, double* __restrict__ rqd) {
  int bid = blockIdx.x;           // token*NH + head
  int tok = bid >> 3, h = bid & 7;
  int d = threadIdx.x;
  double v = (double)q[(size_t)tok * NE + h * ND + d];
  double ss = v * v;
#pragma unroll
  for (int o = 32; o; o >>= 1) ss += __shfl_xor(ss, o);
  if (d == 0) rqd[bid] = 1.0 / (sqrt(ss) + 1e-8);
}

// ---------------- routing, all heads: fp64 dists + top-64 (lowest-index tiebreak) ----------------
__global__ __launch_bounds__(256) void route_kernel(
    const float* __restrict__ q, const double* __restrict__ mnd,
    const double* __restrict__ rqd, int* __restrict__ idxout) {
  __shared__ unsigned long long keys[NS];   // 32 KB
  __shared__ unsigned long long wred[4];
  __shared__ double mc[ND];
  int bhc = blockIdx.x;                     // (b*NH + h)*NC + c
  int c = bhc & (NC - 1);
  int h = (bhc >> 6) & (NH - 1);
  int b = bhc >> 9;
  int t = threadIdx.x;
  if (t < ND) mc[t] = mnd[((size_t)h * NC + c) * ND + t];
  __syncthreads();
  for (int n = t; n < NS; n += 256) {
    const float* qp = q + (size_t)(b * NS + n) * NE + h * ND;
    double acc = 0.0;
#pragma unroll
    for (int d = 0; d < ND; d++) acc += (double)qp[d] * mc[d];
    double dist = acc * rqd[(size_t)(b * NS + n) * NH + h];
    long long sb = __double_as_longlong(dist);
    unsigned long long u = (unsigned long long)sb;
    u = (sb < 0) ? ~u : (u | 0x8000000000000000ULL);
    keys[n] = (u & 0xFFFFFFFFFFFFF000ULL) | (unsigned long long)(NS - 1 - n);
  }
  __syncthreads();
  for (int it = 0; it < NW; it++) {
    unsigned long long best = 0;
    for (int n = t; n < NS; n += 256) { if (keys[n] > best) best = keys[n]; }
#pragma unroll
    for (int o = 32; o; o >>= 1) {
      unsigned long long ot = __shfl_down(best, o);
      if (ot > best) best = ot;
    }
    if ((t & 63) == 0) wred[t >> 6] = best;
    __syncthreads();
    if (t == 0) {
      best = wred[0];
      for (int w = 1; w < 4; w++) if (wred[w] > best) best = wred[w];
      int n = (NS - 1) - (int)(best & 0xFFFULL);
      idxout[(size_t)bhc * NW + it] = n;
      keys[n] = 0;
    }
    __syncthreads();
  }
}

// ---------------- per-(token,head) selection count ----------------
__global__ __launch_bounds__(256) void cnt_kernel(const int* __restrict__ idxb, float* __restrict__ cnt) {
  int i = blockIdx.x * 256 + threadIdx.x;   // NB*NH*NC*NW = 131072
  int bhc = i >> 6;
  int h = (bhc >> 6) & (NH - 1);
  int b = bhc >> 9;
  atomicAdd(&cnt[(size_t)(b * NS + idxb[i]) * NH + h], 1.0f);
}

// ---------------- bucket attention, all heads; scatter (attn/cnt) into obuf (pre-Wo) ----------------
__global__ __launch_bounds__(256) void attn_kernel(
    const float* __restrict__ q, const float* __restrict__ k, const float* __restrict__ v,
    const int* __restrict__ idxb, const int* __restrict__ value, const float* __restrict__ cnt,
    float* __restrict__ obuf) {
  __shared__ float qs[NW * (ND + 1)];   // q, later attn@V result
  __shared__ float ks[NW * (ND + 1)];   // k, later v
  __shared__ float sc[NW * (NW + 1)];
  __shared__ int idxs[NW];
  __shared__ float kmv[NW];
  __shared__ float cinv[NW];
  int bhc = blockIdx.x;                 // (b*NH + h)*NC + c
  int h = (bhc >> 6) & (NH - 1);
  int b = bhc >> 9;
  int t = threadIdx.x;
  if (t < NW) {
    int n = idxb[(size_t)bhc * NW + t];
    idxs[t] = n;
    kmv[t] = (value[b * NS + n] != 0) ? 1.f : 0.f;
    cinv[t] = 1.0f / fmaxf(cnt[(size_t)(b * NS + n) * NH + h], 1.0f);
  }
  __syncthreads();
  for (int p = t; p < NW * ND; p += 256) {
    int w = p >> 6, d = p & (ND - 1);
    size_t src = (size_t)(b * NS + idxs[w]) * NE + h * ND + d;
    qs[w * (ND + 1) + d] = q[src];
    ks[w * (ND + 1) + d] = k[src];
  }
  __syncthreads();
  for (int p = t; p < NW * NW; p += 256) {
    int w = p >> 6, x = p & (NW - 1);
    float dot = 0.f;
#pragma unroll 16
    for (int d = 0; d < ND; d++) dot += qs[w * (ND + 1) + d] * ks[x * (ND + 1) + d];
    bool allowed = (idxs[w] >= idxs[x]) && (kmv[x] != 0.f);
    sc[w * (NW + 1) + x] = allowed ? dot * 0.125f : -1e9f;
  }
  __syncthreads();
  // wave 0: softmax rows with 1/cnt folded; other waves stage V into ks (ks reads done)
  if (t < NW) {
    float mx = -3.4e38f;
    for (int x = 0; x < NW; x++) mx = fmaxf(mx, sc[t * (NW + 1) + x]);
    float sum = 0.f;
    for (int x = 0; x < NW; x++) {
      float e = expf(sc[t * (NW + 1) + x] - mx);
      sc[t * (NW + 1) + x] = e;
      sum += e;
    }
    float inv = cinv[t] / sum;
    for (int x = 0; x < NW; x++) sc[t * (NW + 1) + x] *= inv;
  }
  for (int p = t; p < NW * ND; p += 256) {
    int w = p >> 6, d = p & (ND - 1);
    ks[w * (ND + 1) + d] = v[(size_t)(b * NS + idxs[w]) * NE + h * ND + d];
  }
  __syncthreads();
  // P @ V into qs (old q values dead)
  for (int p = t; p < NW * ND; p += 256) {
    int w = p >> 6, d = p & (ND - 1);
    float o = 0.f;
#pragma unroll 16
    for (int x = 0; x < NW; x++) o += sc[w * (NW + 1) + x] * ks[x * (ND + 1) + d];
    qs[w * (ND + 1) + d] = o;
  }
  __syncthreads();
  // scatter-add pre-Wo outputs (scatter-mean already folded via cinv)
  for (int p = t; p < NW * ND; p += 256) {
    int w = p >> 6, d = p & (ND - 1);
    atomicAdd(&obuf[(size_t)(b * NS + idxs[w]) * NE + h * ND + d], qs[w * (ND + 1) + d]);
  }
}

// ---------------- head: out[b,s,v] = x . head_w[v]; dtype-aware output ----------------
__global__ __launch_bounds__(256) void head_kernel(
    const float* __restrict__ x, const void* __restrict__ hw, void* __restrict__ out,
    const int* __restrict__ dflag) {
  int f32 = dflag[0];
  int gw = (blockIdx.x * 256 + threadIdx.x) >> 6;
  int lane = threadIdx.x & 63;
  if (gw >= NTOK * NVOC) return;
  int row = gw / NVOC, vv = gw % NVOC;
  const float* xr = x + (size_t)row * NE;
  float acc = 0.f;
  for (int e = lane; e < NE; e += 64) acc += xr[e] * ldw(hw, (size_t)vv * NE + e, f32);
#pragma unroll
  for (int o = 32; o; o >>= 1) acc += __shfl_down(acc, o);
  if (lane == 0) {
    if (f32) ((float*)out)[(size_t)row * NVOC + vv] = acc;
    else ((bf16*)out)[(size_t)row * NVOC + vv] = __float2bfloat16(acc);
  }
}

extern "C" void kernel_launch(void* const* d_in, const int* in_sizes, int n_in,
                              void* d_out, int out_size, void* d_ws, size_t ws_size,
                              hipStream_t stream) {
  const int* value = (const int*)d_in[0];
  const int* depth = (const int*)d_in[1];
  const int* pos = (const int*)d_in[2];
  const void* sos = d_in[3];
  const void* tok_emb = d_in[4];
  const void* depth_emb = d_in[5];
  const void* pos_emb = d_in[6];
  const void* ln1_s = d_in[7];
  const void* ln1_b = d_in[8];
  const void* Wq = d_in[9];
  const void* Wk = d_in[10];
  const void* Wv = d_in[11];
  const void* Wo = d_in[12];
  const void* means = d_in[13];
  const void* ln2_s = d_in[14];
  const void* ln2_b = d_in[15];
  const void* W1 = d_in[16];
  const void* b1 = d_in[17];
  const void* W2 = d_in[18];
  const void* b2 = d_in[19];
  const void* head_w = d_in[20];
  (void)in_sizes; (void)n_in;

  const size_t NX = (size_t)NTOK * NE;                 // 8,388,608 floats (32 MiB)

  // layout: x(32M) h/obuf(32M) q(32M) k(32M) v(32M) + mnd(1M) rqd(1M) cnt(.5M) idx(.5M) + dflag
  const size_t NEED = 170917896ULL;                    // ~163.0 MiB
  if (ws_size < NEED) {
    // diagnostic: encode ws MiB into output (finite; fails test but reports budget)
    float val = (float)(unsigned)(ws_size >> 20) * 1000.0f;
    fill_out_kernel<<<(out_size + 255) / 256, 256, 0, stream>>>((float*)d_out, out_size, val);
    return;
  }

  float* xbuf = (float*)d_ws;
  float* hbuf = xbuf + NX;       // LN1 output, then reused as pre-Wo attn accumulator (obuf)
  float* qbuf = hbuf + NX;       // q all heads; later LN2 output
  float* kbuf = qbuf + NX;       // k all heads; kbuf..vbuf doubles as FFN mid (64 MiB)
  float* vbuf = kbuf + NX;       // v all heads
  double* mndbuf = (double*)(vbuf + NX);
  double* rqdbuf = mndbuf + (size_t)NL * NH * NC * ND;
  float* cntbuf = (float*)(rqdbuf + (size_t)NTOK * NH);
  int* idxbuf = (int*)(cntbuf + (size_t)NTOK * NH);
  int* dflag = idxbuf + (size_t)NB * NH * NC * NW;
  float* mid = kbuf;             // 8192 x 2048 fp32 = 64 MiB (k,v dead during FFN)

  detect_kernel<<<1, 64, 0, stream>>>(tok_emb, dflag);
  mnd_kernel<<<NL * NH * NC, 64, 0, stream>>>(means, mndbuf, dflag);
  embed_kernel<<<(int)((NX + 255) / 256), 256, 0, stream>>>(
      value, depth, pos, sos, tok_emb, depth_emb, pos_emb, xbuf, dflag);

  const int CH = 8192;           // FFN row chunk (mid = CH x NF = 64 MiB)
  dim3 gqkv(NE / 128, NTOK / 128);           // (4, 128)
  dim3 gW1(NF / 128, CH / 128);              // (16, 64)
  dim3 gW2(NE / 128, CH / 128);              // (4, 64)

  for (int l = 0; l < NL; l++) {
    size_t o_w = (size_t)l * NE * NE;
    size_t o_w1 = (size_t)l * NE * NF;
    size_t o_w2 = (size_t)l * NF * NE;
    size_t o_e = (size_t)l * NE;
    size_t o_f = (size_t)l * NF;

    // h = LN1(x)
    ln_kernel<<<NTOK, 256, 0, stream>>>(xbuf, ln1_s, ln1_b, o_e, hbuf, dflag);

    // full-width q,k,v
    gemm_kernel<0><<<gqkv, 256, 0, stream>>>(hbuf, Wq, o_w, NE, nullptr, 0, nullptr,
                                             qbuf, NTOK, NE, NE, dflag);
    gemm_kernel<0><<<gqkv, 256, 0, stream>>>(hbuf, Wk, o_w, NE, nullptr, 0, nullptr,
                                             kbuf, NTOK, NE, NE, dflag);
    gemm_kernel<0><<<gqkv, 256, 0, stream>>>(hbuf, Wv, o_w, NE, nullptr, 0, nullptr,
                                             vbuf, NTOK, NE, NE, dflag);

    // routing (all heads)
    rq_kernel<<<NTOK * NH, 64, 0, stream>>>(qbuf, rqdbuf);
    route_kernel<<<NB * NH * NC, 256, 0, stream>>>(
        qbuf, mndbuf + (size_t)l * NH * NC * ND, rqdbuf, idxbuf);
    zero_kernel<<<(NTOK * NH) / 256, 256, 0, stream>>>(cntbuf, NTOK * NH);
    cnt_kernel<<<(NB * NH * NC * NW) / 256, 256, 0, stream>>>(idxbuf, cntbuf);

    // attention into obuf (= hbuf, dead after the QKV GEMMs), then Wo GEMM with residual
    zero_kernel<<<(int)((NX + 255) / 256), 256, 0, stream>>>(hbuf, (int)NX);
    attn_kernel<<<NB * NH * NC, 256, 0, stream>>>(qbuf, kbuf, vbuf, idxbuf, value, cntbuf, hbuf);
    gemm_kernel<0><<<gqkv, 256, 0, stream>>>(hbuf, Wo, o_w, NE, nullptr, 0, xbuf,
                                             xbuf, NTOK, NE, NE, dflag);

    // FFN: LN2 into qbuf (dead), mid in k/v region
    ln_kernel<<<NTOK, 256, 0, stream>>>(xbuf, ln2_s, ln2_b, o_e, qbuf, dflag);
    for (int ch = 0; ch < NTOK / CH; ch++) {
      const float* hch = qbuf + (size_t)ch * CH * NE;
      float* xch = xbuf + (size_t)ch * CH * NE;
      gemm_kernel<1><<<gW1, 256, 0, stream>>>(hch, W1, o_w1, NF, b1, o_f, nullptr,
                                              mid, CH, NF, NE, dflag);
      gemm_kernel<0><<<gW2, 256, 0, stream>>>(mid, W2, o_w2, NE, b2, o_e, xch,
                                              xch, CH, NE, NF, dflag);
    }
  }

  head_kernel<<<(NTOK * NVOC * 64 + 255) / 256, 256, 0, stream>>>(xbuf, head_w, d_out, dflag);
}

// Round 9
// 9315.643 us; speedup vs baseline: 3.5724x; 1.0056x over previous
//
#include <hip/hip_runtime.h>
#include <hip/hip_bf16.h>
#include <math.h>

typedef __hip_bfloat16 bf16;

#define NB 4
#define NS 4096
#define NE 512
#define NH 8
#define NL 4
#define NA 3
#define ND 64
#define NC 64
#define NW 64
#define NF 2048
#define NVOC 17
#define NTOK (NB * NS)   // 16384

__device__ __forceinline__ float b2f(bf16 v) { return __bfloat162float(v); }
__device__ __forceinline__ float u2f(unsigned short u) { return __uint_as_float((unsigned)u << 16); }
// dual-dtype scalar load: f32 ? float : bf16
__device__ __forceinline__ float ldw(const void* p, size_t i, int f32) {
  return f32 ? ((const float*)p)[i] : b2f(((const bf16*)p)[i]);
}

// ---------------- dtype detect (tok_emb row 0 all-zero <=> fp32 spans words 0..511) ----------------
__global__ void detect_kernel(const void* __restrict__ tok, int* __restrict__ dflag) {
  if (threadIdx.x == 0 && blockIdx.x == 0) {
    const unsigned* w = (const unsigned*)tok;
    int any = 0;
    for (int i = 256; i < 512; i++) any |= (w[i] != 0u);
    dflag[0] = any ? 0 : 1;   // 1 = fp32 inputs, 0 = bf16 inputs
  }
}

// ---------------- diagnostic fill (ws_size too small) ----------------
__global__ __launch_bounds__(256) void fill_out_kernel(float* __restrict__ out, int n, float val) {
  int i = blockIdx.x * 256 + threadIdx.x;
  if (i < n) out[i] = val;
}

// ---------------- zero fill ----------------
__global__ __launch_bounds__(256) void zero_kernel(float* __restrict__ p, int n) {
  int i = blockIdx.x * 256 + threadIdx.x;
  if (i < n) p[i] = 0.f;
}

// ---------------- embeddings + shift-right ----------------
__global__ __launch_bounds__(256) void embed_kernel(
    const int* __restrict__ value, const int* __restrict__ depth, const int* __restrict__ pos,
    const void* __restrict__ sos, const void* __restrict__ tok_emb,
    const void* __restrict__ depth_emb, const void* __restrict__ pos_emb,
    float* __restrict__ x, const int* __restrict__ dflag) {
  int f32 = dflag[0];
  int i = blockIdx.x * 256 + threadIdx.x;
  if (i >= NTOK * NE) return;
  int e = i & (NE - 1);
  int bs = i >> 9;
  int s = bs & (NS - 1);
  int b = bs >> 12;
  float v;
  if (s == 0) {
    v = ldw(sos, e, f32);
  } else {
    int src = b * NS + (s - 1);
    float acc = ldw(tok_emb, (size_t)value[src] * NE + e, f32)
              + ldw(depth_emb, (size_t)depth[src] * NE + e, f32);
#pragma unroll
    for (int a = 0; a < NA; a++)
      acc += ldw(pos_emb, ((size_t)a * 65 + pos[src * NA + a]) * NE + e, f32);
    v = acc;
  }
  x[i] = v;
}

// ---------------- layer norm, one wave per row (shfl reductions, no barriers) ----------------
__global__ __launch_bounds__(256) void ln_kernel(
    const float* __restrict__ x, const void* __restrict__ gam, const void* __restrict__ bet,
    size_t off, float* __restrict__ out, const int* __restrict__ dflag) {
  int f32 = dflag[0];
  int row = blockIdx.x * 4 + (threadIdx.x >> 6);
  int lane = threadIdx.x & 63;
  const float* xr = x + (size_t)row * NE;
  float v[8];
#pragma unroll
  for (int i = 0; i < 8; i++) v[i] = xr[lane + i * 64];
  float s = 0.f;
#pragma unroll
  for (int i = 0; i < 8; i++) s += v[i];
#pragma unroll
  for (int o = 32; o; o >>= 1) s += __shfl_xor(s, o);
  float m = s * (1.0f / NE);
  float sq = 0.f;
#pragma unroll
  for (int i = 0; i < 8; i++) { float d = v[i] - m; sq += d * d; }
#pragma unroll
  for (int o = 32; o; o >>= 1) sq += __shfl_xor(sq, o);
  float rs = 1.0f / sqrtf(sq * (1.0f / NE) + 1e-5f);
  float* orow = out + (size_t)row * NE;
#pragma unroll
  for (int i = 0; i < 8; i++) {
    int e = lane + i * 64;
    orow[e] = (v[i] - m) * rs * ldw(gam, off + e, f32) + ldw(bet, off + e, f32);
  }
}

// ---------------- GEMM 128x128 tile, 8x8 microtile, conflict-free b-reads, reg prefetch ----------
// C(MxN) = act(A @ B + bias) [+resid]; A fp32 MxK; B (bf16|f32) base+elem offset, row stride ldb.
// Thread covers rows bm+ty*8..+7, cols bn + {tx*4..+3, 64+tx*4..+3}.
template <int ACT>
__global__ __launch_bounds__(256) void gemm_kernel(
    const float* __restrict__ A, const void* __restrict__ Bw, size_t bwoff, int ldb,
    const void* bias, size_t biasoff, const float* resid, float* C,
    int M, int N, int K, const int* __restrict__ dflag) {
  __shared__ float As[16][132];   // [k][m]
  __shared__ float Bs[16][132];   // [k][n]
  int f32 = dflag[0];
  int tid = threadIdx.x;
  int bm = blockIdx.y << 7, bn = blockIdx.x << 7;
  int ty = tid >> 4, tx = tid & 15;
  float acc[8][8];
#pragma unroll
  for (int i = 0; i < 8; i++)
#pragma unroll
    for (int j = 0; j < 8; j++) acc[i][j] = 0.f;
  int arow = tid >> 1;            // 0..127
  int acol = (tid & 1) << 3;      // 0 | 8
  int brow = tid >> 4;            // 0..15
  int bcol = (tid & 15) << 3;     // 0..120

  const float* Aptr = A + (size_t)(bm + arow) * K + acol;
  // prefetch tile 0
  float4 pa0 = *(const float4*)(Aptr);
  float4 pa1 = *(const float4*)(Aptr + 4);
  float4 pb0, pb1;
  uint4 pbu;
  {
    size_t boff = bwoff + (size_t)brow * ldb + bn + bcol;
    if (f32) {
      pb0 = *(const float4*)((const float*)Bw + boff);
      pb1 = *(const float4*)((const float*)Bw + boff + 4);
    } else {
      pbu = *(const uint4*)((const bf16*)Bw + boff);
    }
  }

  for (int k0 = 0; k0 < K; k0 += 16) {
    // commit prefetched tile to LDS
    As[acol + 0][arow] = pa0.x; As[acol + 1][arow] = pa0.y;
    As[acol + 2][arow] = pa0.z; As[acol + 3][arow] = pa0.w;
    As[acol + 4][arow] = pa1.x; As[acol + 5][arow] = pa1.y;
    As[acol + 6][arow] = pa1.z; As[acol + 7][arow] = pa1.w;
    if (f32) {
      Bs[brow][bcol + 0] = pb0.x; Bs[brow][bcol + 1] = pb0.y;
      Bs[brow][bcol + 2] = pb0.z; Bs[brow][bcol + 3] = pb0.w;
      Bs[brow][bcol + 4] = pb1.x; Bs[brow][bcol + 5] = pb1.y;
      Bs[brow][bcol + 6] = pb1.z; Bs[brow][bcol + 7] = pb1.w;
    } else {
      union { uint4 u; unsigned short s[8]; } r; r.u = pbu;
#pragma unroll
      for (int j = 0; j < 8; j++) Bs[brow][bcol + j] = u2f(r.s[j]);
    }
    __syncthreads();
    // prefetch next tile (overlaps with compute below)
    if (k0 + 16 < K) {
      pa0 = *(const float4*)(Aptr + k0 + 16);
      pa1 = *(const float4*)(Aptr + k0 + 20);
      size_t boff = bwoff + (size_t)(k0 + 16 + brow) * ldb + bn + bcol;
      if (f32) {
        pb0 = *(const float4*)((const float*)Bw + boff);
        pb1 = *(const float4*)((const float*)Bw + boff + 4);
      } else {
        pbu = *(const uint4*)((const bf16*)Bw + boff);
      }
    }
#pragma unroll
    for (int kk = 0; kk < 16; kk++) {
      float4 aA = *(const float4*)&As[kk][ty << 3];
      float4 aB = *(const float4*)&As[kk][(ty << 3) + 4];
      float4 bA = *(const float4*)&Bs[kk][tx << 2];          // cols tx*4..+3
      float4 bB = *(const float4*)&Bs[kk][64 + (tx << 2)];   // cols 64+tx*4..+3
      float av[8] = {aA.x, aA.y, aA.z, aA.w, aB.x, aB.y, aB.z, aB.w};
      float bv[8] = {bA.x, bA.y, bA.z, bA.w, bB.x, bB.y, bB.z, bB.w};
#pragma unroll
      for (int i = 0; i < 8; i++)
#pragma unroll
        for (int j = 0; j < 8; j++)
          acc[i][j] += av[i] * bv[j];
    }
    __syncthreads();
  }
  // epilogue: two float4 stores per row
#pragma unroll
  for (int i = 0; i < 8; i++) {
    int row = bm + (ty << 3) + i;
    int c0 = bn + (tx << 2);
    int c1 = bn + 64 + (tx << 2);
    float o0[4], o1[4];
#pragma unroll
    for (int j = 0; j < 4; j++) { o0[j] = acc[i][j]; o1[j] = acc[i][j + 4]; }
    if (bias) {
#pragma unroll
      for (int j = 0; j < 4; j++) {
        o0[j] += ldw(bias, biasoff + c0 + j, f32);
        o1[j] += ldw(bias, biasoff + c1 + j, f32);
      }
    }
    if (ACT == 1) {
#pragma unroll
      for (int j = 0; j < 4; j++) {
        float t0 = 0.7978845608028654f * (o0[j] + 0.044715f * o0[j] * o0[j] * o0[j]);
        o0[j] = 0.5f * o0[j] * (1.0f + tanhf(t0));
        float t1 = 0.7978845608028654f * (o1[j] + 0.044715f * o1[j] * o1[j] * o1[j]);
        o1[j] = 0.5f * o1[j] * (1.0f + tanhf(t1));
      }
    }
    size_t p0 = (size_t)row * N + c0;
    size_t p1 = (size_t)row * N + c1;
    if (resid) {
      float4 r0 = *(const float4*)(resid + p0);
      float4 r1 = *(const float4*)(resid + p1);
      o0[0] += r0.x; o0[1] += r0.y; o0[2] += r0.z; o0[3] += r0.w;
      o1[0] += r1.x; o1[1] += r1.y; o1[2] += r1.z; o1[3] += r1.w;
    }
    *(float4*)(C + p0) = make_float4(o0[0], o0[1], o0[2], o0[3]);
    *(float4*)(C + p1) = make_float4(o1[0], o1[1], o1[2], o1[3]);
  }
}

// ---------------- normalized means in fp64 ----------------
__global__ __launch_bounds__(64) void mnd_kernel(const void* __restrict__ means,
                                                 double* __restrict__ mnd,
                                                 const int* __restrict__ dflag) {
  __shared__ double s[64];
  int f32 = dflag[0];
  int vblk = blockIdx.x;          // (l*NH + h)*NC + c
  int d = threadIdx.x;
  double m = (double)ldw(means, (size_t)vblk * ND + d, f32);
  s[d] = m * m;
  __syncthreads();
  for (int st = 32; st; st >>= 1) { if (d < st) s[d] += s[d + st]; __syncthreads(); }
  mnd[(size_t)vblk * ND + d] = m / (sqrt(s[0]) + 1e-8);
}

// ---------------- per-(token,head) 1/(||q||+1e-8) ----------------
__global__ __launch_bounds__(64) void rq_kernel(const float* __restrict__ q, double* __restrict__ rqd) {
  int bid = blockIdx.x;           // token*NH + head
  int tok = bid >> 3, h = bid & 7;
  int d = threadIdx.x;
  double v = (double)q[(size_t)tok * NE + h * ND + d];
  double ss = v * v;
#pragma unroll
  for (int o = 32; o; o >>= 1) ss += __shfl_xor(ss, o);
  if (d == 0) rqd[bid] = 1.0 / (sqrt(ss) + 1e-8);
}

// ---------------- routing, all heads: fp64 dists + top-64 (cached-max selection) ----------------
__global__ __launch_bounds__(256) void route_kernel(
    const float* __restrict__ q, const double* __restrict__ mnd,
    const double* __restrict__ rqd, int* __restrict__ idxout) {
  __shared__ unsigned long long keys[NS];   // 32 KB
  __shared__ unsigned long long wred[4];
  __shared__ double mc[ND];
  __shared__ int winner;
  int bhc = blockIdx.x;                     // (b*NH + h)*NC + c
  int c = bhc & (NC - 1);
  int h = (bhc >> 6) & (NH - 1);
  int b = bhc >> 9;
  int t = threadIdx.x;
  if (t < ND) mc[t] = mnd[((size_t)h * NC + c) * ND + t];
  __syncthreads();
  for (int n = t; n < NS; n += 256) {
    const float* qp = q + (size_t)(b * NS + n) * NE + h * ND;
    double a0 = 0.0, a1 = 0.0, a2 = 0.0, a3 = 0.0;
#pragma unroll
    for (int d = 0; d < ND; d += 4) {
      a0 += (double)qp[d + 0] * mc[d + 0];
      a1 += (double)qp[d + 1] * mc[d + 1];
      a2 += (double)qp[d + 2] * mc[d + 2];
      a3 += (double)qp[d + 3] * mc[d + 3];
    }
    double dist = ((a0 + a1) + (a2 + a3)) * rqd[(size_t)(b * NS + n) * NH + h];
    long long sb = __double_as_longlong(dist);
    unsigned long long u = (unsigned long long)sb;
    u = (sb < 0) ? ~u : (u | 0x8000000000000000ULL);
    keys[n] = (u & 0xFFFFFFFFFFFFF000ULL) | (unsigned long long)(NS - 1 - n);
  }
  __syncthreads();
  // per-thread cached max over its slice (n ≡ t mod 256)
  unsigned long long lm = 0;
  for (int n = t; n < NS; n += 256) { if (keys[n] > lm) lm = keys[n]; }
  for (int it = 0; it < NW; it++) {
    unsigned long long best = lm;
#pragma unroll
    for (int o = 32; o; o >>= 1) {
      unsigned long long ot = __shfl_down(best, o);
      if (ot > best) best = ot;
    }
    if ((t & 63) == 0) wred[t >> 6] = best;
    __syncthreads();
    if (t == 0) {
      best = wred[0];
      for (int w = 1; w < 4; w++) if (wred[w] > best) best = wred[w];
      int n = (NS - 1) - (int)(best & 0xFFFULL);
      idxout[(size_t)bhc * NW + it] = n;
      keys[n] = 0;
      winner = n;
    }
    __syncthreads();
    if ((winner & 255) == t) {      // only the owner's cache is stale
      lm = 0;
      for (int n = t; n < NS; n += 256) { if (keys[n] > lm) lm = keys[n]; }
    }
  }
}

// ---------------- per-(token,head) selection count ----------------
__global__ __launch_bounds__(256) void cnt_kernel(const int* __restrict__ idxb, float* __restrict__ cnt) {
  int i = blockIdx.x * 256 + threadIdx.x;   // NB*NH*NC*NW = 131072
  int bhc = i >> 6;
  int h = (bhc >> 6) & (NH - 1);
  int b = bhc >> 9;
  atomicAdd(&cnt[(size_t)(b * NS + idxb[i]) * NH + h], 1.0f);
}

// ---------------- bucket attention, all heads; scatter (attn/cnt) into obuf (pre-Wo) ----------------
__global__ __launch_bounds__(256) void attn_kernel(
    const float* __restrict__ q, const float* __restrict__ k, const float* __restrict__ v,
    const int* __restrict__ idxb, const int* __restrict__ value, const float* __restrict__ cnt,
    float* __restrict__ obuf) {
  __shared__ float qs[NW * (ND + 1)];   // q, later attn@V result
  __shared__ float ks[NW * (ND + 1)];   // k, later v
  __shared__ float sc[NW * (NW + 1)];
  __shared__ int idxs[NW];
  __shared__ float kmv[NW];
  __shared__ float cinv[NW];
  int bhc = blockIdx.x;                 // (b*NH + h)*NC + c
  int h = (bhc >> 6) & (NH - 1);
  int b = bhc >> 9;
  int t = threadIdx.x;
  if (t < NW) {
    int n = idxb[(size_t)bhc * NW + t];
    idxs[t] = n;
    kmv[t] = (value[b * NS + n] != 0) ? 1.f : 0.f;
    cinv[t] = 1.0f / fmaxf(cnt[(size_t)(b * NS + n) * NH + h], 1.0f);
  }
  __syncthreads();
  for (int p = t; p < NW * ND; p += 256) {
    int w = p >> 6, d = p & (ND - 1);
    size_t src = (size_t)(b * NS + idxs[w]) * NE + h * ND + d;
    qs[w * (ND + 1) + d] = q[src];
    ks[w * (ND + 1) + d] = k[src];
  }
  __syncthreads();
  for (int p = t; p < NW * NW; p += 256) {
    int w = p >> 6, x = p & (NW - 1);
    float dot = 0.f;
#pragma unroll 16
    for (int d = 0; d < ND; d++) dot += qs[w * (ND + 1) + d] * ks[x * (ND + 1) + d];
    bool allowed = (idxs[w] >= idxs[x]) && (kmv[x] != 0.f);
    sc[w * (NW + 1) + x] = allowed ? dot * 0.125f : -1e9f;
  }
  __syncthreads();
  // wave 0: softmax rows with 1/cnt folded; other waves stage V into ks (ks reads done)
  if (t < NW) {
    float mx = -3.4e38f;
    for (int x = 0; x < NW; x++) mx = fmaxf(mx, sc[t * (NW + 1) + x]);
    float sum = 0.f;
    for (int x = 0; x < NW; x++) {
      float e = expf(sc[t * (NW + 1) + x] - mx);
      sc[t * (NW + 1) + x] = e;
      sum += e;
    }
    float inv = cinv[t] / sum;
    for (int x = 0; x < NW; x++) sc[t * (NW + 1) + x] *= inv;
  }
  for (int p = t; p < NW * ND; p += 256) {
    int w = p >> 6, d = p & (ND - 1);
    ks[w * (ND + 1) + d] = v[(size_t)(b * NS + idxs[w]) * NE + h * ND + d];
  }
  __syncthreads();
  // P @ V into qs (old q values dead)
  for (int p = t; p < NW * ND; p += 256) {
    int w = p >> 6, d = p & (ND - 1);
    float o = 0.f;
#pragma unroll 16
    for (int x = 0; x < NW; x++) o += sc[w * (NW + 1) + x] * ks[x * (ND + 1) + d];
    qs[w * (ND + 1) + d] = o;
  }
  __syncthreads();
  // scatter-add pre-Wo outputs (scatter-mean already folded via cinv)
  for (int p = t; p < NW * ND; p += 256) {
    int w = p >> 6, d = p & (ND - 1);
    atomicAdd(&obuf[(size_t)(b * NS + idxs[w]) * NE + h * ND + d], qs[w * (ND + 1) + d]);
  }
}

// ---------------- head: out[b,s,v] = x . head_w[v]; dtype-aware output ----------------
__global__ __launch_bounds__(256) void head_kernel(
    const float* __restrict__ x, const void* __restrict__ hw, void* __restrict__ out,
    const int* __restrict__ dflag) {
  int f32 = dflag[0];
  int gw = (blockIdx.x * 256 + threadIdx.x) >> 6;
  int lane = threadIdx.x & 63;
  if (gw >= NTOK * NVOC) return;
  int row = gw / NVOC, vv = gw % NVOC;
  const float* xr = x + (size_t)row * NE;
  float acc = 0.f;
  for (int e = lane; e < NE; e += 64) acc += xr[e] * ldw(hw, (size_t)vv * NE + e, f32);
#pragma unroll
  for (int o = 32; o; o >>= 1) acc += __shfl_down(acc, o);
  if (lane == 0) {
    if (f32) ((float*)out)[(size_t)row * NVOC + vv] = acc;
    else ((bf16*)out)[(size_t)row * NVOC + vv] = __float2bfloat16(acc);
  }
}

extern "C" void kernel_launch(void* const* d_in, const int* in_sizes, int n_in,
                              void* d_out, int out_size, void* d_ws, size_t ws_size,
                              hipStream_t stream) {
  const int* value = (const int*)d_in[0];
  const int* depth = (const int*)d_in[1];
  const int* pos = (const int*)d_in[2];
  const void* sos = d_in[3];
  const void* tok_emb = d_in[4];
  const void* depth_emb = d_in[5];
  const void* pos_emb = d_in[6];
  const void* ln1_s = d_in[7];
  const void* ln1_b = d_in[8];
  const void* Wq = d_in[9];
  const void* Wk = d_in[10];
  const void* Wv = d_in[11];
  const void* Wo = d_in[12];
  const void* means = d_in[13];
  const void* ln2_s = d_in[14];
  const void* ln2_b = d_in[15];
  const void* W1 = d_in[16];
  const void* b1 = d_in[17];
  const void* W2 = d_in[18];
  const void* b2 = d_in[19];
  const void* head_w = d_in[20];
  (void)in_sizes; (void)n_in;

  const size_t NX = (size_t)NTOK * NE;                 // 8,388,608 floats (32 MiB)

  const size_t NEED = 170917896ULL;                    // ~163.0 MiB
  if (ws_size < NEED) {
    float val = (float)(unsigned)(ws_size >> 20) * 1000.0f;
    fill_out_kernel<<<(out_size + 255) / 256, 256, 0, stream>>>((float*)d_out, out_size, val);
    return;
  }

  float* xbuf = (float*)d_ws;
  float* hbuf = xbuf + NX;       // LN1 output, then reused as pre-Wo attn accumulator (obuf)
  float* qbuf = hbuf + NX;       // q all heads; later LN2 output
  float* kbuf = qbuf + NX;       // k all heads; kbuf..vbuf doubles as FFN mid (64 MiB)
  float* vbuf = kbuf + NX;       // v all heads
  double* mndbuf = (double*)(vbuf + NX);
  double* rqdbuf = mndbuf + (size_t)NL * NH * NC * ND;
  float* cntbuf = (float*)(rqdbuf + (size_t)NTOK * NH);
  int* idxbuf = (int*)(cntbuf + (size_t)NTOK * NH);
  int* dflag = idxbuf + (size_t)NB * NH * NC * NW;
  float* mid = kbuf;             // 8192 x 2048 fp32 = 64 MiB (k,v dead during FFN)

  detect_kernel<<<1, 64, 0, stream>>>(tok_emb, dflag);
  mnd_kernel<<<NL * NH * NC, 64, 0, stream>>>(means, mndbuf, dflag);
  embed_kernel<<<(int)((NX + 255) / 256), 256, 0, stream>>>(
      value, depth, pos, sos, tok_emb, depth_emb, pos_emb, xbuf, dflag);

  const int CH = 8192;           // FFN row chunk (mid = CH x NF = 64 MiB)
  dim3 gqkv(NE / 128, NTOK / 128);           // (4, 128)
  dim3 gW1(NF / 128, CH / 128);              // (16, 64)
  dim3 gW2(NE / 128, CH / 128);              // (4, 64)

  for (int l = 0; l < NL; l++) {
    size_t o_w = (size_t)l * NE * NE;
    size_t o_w1 = (size_t)l * NE * NF;
    size_t o_w2 = (size_t)l * NF * NE;
    size_t o_e = (size_t)l * NE;
    size_t o_f = (size_t)l * NF;

    // h = LN1(x)
    ln_kernel<<<NTOK / 4, 256, 0, stream>>>(xbuf, ln1_s, ln1_b, o_e, hbuf, dflag);

    // full-width q,k,v
    gemm_kernel<0><<<gqkv, 256, 0, stream>>>(hbuf, Wq, o_w, NE, nullptr, 0, nullptr,
                                             qbuf, NTOK, NE, NE, dflag);
    gemm_kernel<0><<<gqkv, 256, 0, stream>>>(hbuf, Wk, o_w, NE, nullptr, 0, nullptr,
                                             kbuf, NTOK, NE, NE, dflag);
    gemm_kernel<0><<<gqkv, 256, 0, stream>>>(hbuf, Wv, o_w, NE, nullptr, 0, nullptr,
                                             vbuf, NTOK, NE, NE, dflag);

    // routing (all heads)
    rq_kernel<<<NTOK * NH, 64, 0, stream>>>(qbuf, rqdbuf);
    route_kernel<<<NB * NH * NC, 256, 0, stream>>>(
        qbuf, mndbuf + (size_t)l * NH * NC * ND, rqdbuf, idxbuf);
    zero_kernel<<<(NTOK * NH) / 256, 256, 0, stream>>>(cntbuf, NTOK * NH);
    cnt_kernel<<<(NB * NH * NC * NW) / 256, 256, 0, stream>>>(idxbuf, cntbuf);

    // attention into obuf (= hbuf, dead after the QKV GEMMs), then Wo GEMM with residual
    zero_kernel<<<(int)((NX + 255) / 256), 256, 0, stream>>>(hbuf, (int)NX);
    attn_kernel<<<NB * NH * NC, 256, 0, stream>>>(qbuf, kbuf, vbuf, idxbuf, value, cntbuf, hbuf);
    gemm_kernel<0><<<gqkv, 256, 0, stream>>>(hbuf, Wo, o_w, NE, nullptr, 0, xbuf,
                                             xbuf, NTOK, NE, NE, dflag);

    // FFN: LN2 into qbuf (dead), mid in k/v region
    ln_kernel<<<NTOK / 4, 256, 0, stream>>>(xbuf, ln2_s, ln2_b, o_e, qbuf, dflag);
    for (int ch = 0; ch < NTOK / CH; ch++) {
      const float* hch = qbuf + (size_t)ch * CH * NE;
      float* xch = xbuf + (size_t)ch * CH * NE;
      gemm_kernel<1><<<gW1, 256, 0, stream>>>(hch, W1, o_w1, NF, b1, o_f, nullptr,
                                              mid, CH, NF, NE, dflag);
      gemm_kernel<0><<<gW2, 256, 0, stream>>>(mid, W2, o_w2, NE, b2, o_e, xch,
                                              xch, CH, NE, NF, dflag);
    }
  }

  head_kernel<<<(NTOK * NVOC * 64 + 255) / 256, 256, 0, stream>>>(xbuf, head_w, d_out, dflag);
}